// Round 20
// baseline (305.510 us; speedup 1.0000x reference)
//
#include <hip/hip_runtime.h>
#include <hip/hip_bf16.h>
#include <hip/hip_fp8.h>
#include <stdint.h>
#include <math.h>

#define NN 16384
#define DD 256
#define MARGIN_F 0.2f

typedef __attribute__((ext_vector_type(8))) int int32x8;
typedef __attribute__((ext_vector_type(4))) float f32x4;

// monotone order-preserving float<->uint key (max via unsigned atomicMax)
__device__ inline unsigned fkey(float f) {
    unsigned b = __float_as_uint(f);
    return (b & 0x80000000u) ? ~b : (b | 0x80000000u);
}
__device__ inline float fdec(unsigned k) {
    return __uint_as_float((k & 0x80000000u) ? (k ^ 0x80000000u) : ~k);
}
#define NEG_INF_KEY 0x007FFFFFu   // fkey(-inf)

__device__ inline void gload16(const void* g, void* l) {
    __builtin_amdgcn_global_load_lds(
        (const __attribute__((address_space(1))) void*)g,
        (__attribute__((address_space(3))) void*)l, 16, 0, 0);
}

__device__ inline unsigned pk8(float4 v) {
    __hip_fp8_e4m3 q0(v.x), q1(v.y), q2(v.z), q3(v.w);
    return (unsigned)q0.__x | ((unsigned)q1.__x << 8) |
           ((unsigned)q2.__x << 16) | ((unsigned)q3.__x << 24);
}

// ---------------- fused prep: f32->fp8 e4m3 + diag + init maxes ------------
__global__ __launch_bounds__(256) void fused_prep_kernel(
    const float* __restrict__ imgs, const float* __restrict__ caps,
    unsigned char* __restrict__ imgs8, unsigned char* __restrict__ caps8,
    float* __restrict__ diag, unsigned* __restrict__ rowmax,
    unsigned* __restrict__ colmax) {
    const int i = (blockIdx.x << 2) + (threadIdx.x >> 6);
    const int l = threadIdx.x & 63;
    const float4* a4 = reinterpret_cast<const float4*>(imgs + (size_t)i * DD);
    const float4* b4 = reinterpret_cast<const float4*>(caps + (size_t)i * DD);
    float4 av = a4[l];
    float4 bv = b4[l];
    reinterpret_cast<unsigned*>(imgs8 + (size_t)i * DD)[l] = pk8(av);
    reinterpret_cast<unsigned*>(caps8 + (size_t)i * DD)[l] = pk8(bv);
    float s = av.x * bv.x + av.y * bv.y + av.z * bv.z + av.w * bv.w;
    #pragma unroll
    for (int off = 32; off > 0; off >>= 1) s += __shfl_down(s, off);
    if (l == 0) {
        diag[i] = s;
        rowmax[i] = NEG_INF_KEY;
        colmax[i] = NEG_INF_KEY;
    }
}

// ---------------- main: MX-fp8, B global->VGPR, acc ping-pong --------------
// R18 skeleton (proven 83us): 512 blocks = 128 row-panels(128) x 4 strips;
// A panel (32KB fp8) staged once via gload_lds -> af[8][2]; B fragments
// loaded straight from L2 to VGPRs one chunk ahead; no in-loop barriers.
// NEW: TWO accumulator arrays (accA/accB), h unrolled by 2 -- epilogue of
// chunk h-1 issues right after the MFMA burst of chunk h, so the VALU max
// trees run UNDER the matrix pipe instead of serially after it.
__global__ __launch_bounds__(256, 2) void score_max_kernel(
    const unsigned char* __restrict__ imgs8,
    const unsigned char* __restrict__ caps8,
    const float* __restrict__ diag,
    unsigned* __restrict__ rowmax, unsigned* __restrict__ colmax) {

    __shared__ char lds[49152];   // [0,32K): A staging; [32K,48K): clds
    float* clds = reinterpret_cast<float*>(lds + 32768);

    const int bid   = blockIdx.x;
    const int panel = bid >> 2;
    const int strip = bid & 3;
    const int brow  = panel << 7;       // 128-row panel
    const int scol  = strip << 12;      // 4096-col strip

    const int t    = threadIdx.x;
    const int wid  = t >> 6;      // 0..3: col-slice owner
    const int lane = t & 63;
    const int rg   = lane >> 4;   // 0..3
    const int cl   = lane & 15;   // 0..15

    // ---- init clds (4096 floats) ----
    #pragma unroll
    for (int i = 0; i < 16; ++i) clds[t + (i << 8)] = -INFINITY;

    // ---- stage A panel (128 rows = 32KB) with 32B-pair XOR swizzle ----
    {
        const int sl = t & 15;
        const int rw = t >> 4;
        const int srcoff = (((sl >> 1) ^ (rw & 7)) << 5) + ((sl & 1) << 4);
        const unsigned char* src =
            imgs8 + (((size_t)(brow + rw)) << 8) + srcoff;
        #pragma unroll
        for (int i = 0; i < 8; ++i)
            gload16(src + ((size_t)i << 12), lds + t * 16 + i * 4096);
    }
    __syncthreads();

    // ---- A fragments: af[m][ks], row = m*16+cl (full 128 rows/wave) ----
    int32x8 af[8][2];
    #pragma unroll
    for (int m = 0; m < 8; ++m) {
        const int row = m * 16 + cl;
        #pragma unroll
        for (int ks = 0; ks < 2; ++ks)
            af[m][ks] = *reinterpret_cast<const int32x8*>(
                lds + row * 256 + (((rg + (ks << 2)) ^ (cl & 7)) << 5));
    }
    // no further shared-LDS hazards in loop: clds cols are wave-exclusive

    float rmx[8][4];
    #pragma unroll
    for (int m = 0; m < 8; ++m)
        #pragma unroll
        for (int r = 0; r < 4; ++r) rmx[m][r] = -INFINITY;

    // ---- B base: wave col = scol + wid*16 + cl; 32B at rg*32 ----
    const unsigned char* pb =
        caps8 + (((size_t)(scol + (wid << 4) + cl)) << 8) + (rg << 5);

    const f32x4 zv = (f32x4){0.f, 0.f, 0.f, 0.f};
    #define SCL 0x7F7F7F7F   // E8M0 exponent 127 = 1.0 in every byte

    f32x4 accA[8], accB[8];

    #define MFMA_CHUNK(ACC, B0, B1) {                                          \
        __builtin_amdgcn_s_setprio(1);                                         \
        _Pragma("unroll")                                                      \
        for (int m = 0; m < 8; ++m)                                            \
            ACC[m] = __builtin_amdgcn_mfma_scale_f32_16x16x128_f8f6f4(         \
                af[m][0], B0, zv, 0, 0, 0, SCL, 0, SCL);                       \
        _Pragma("unroll")                                                      \
        for (int m = 0; m < 8; ++m)                                            \
            ACC[m] = __builtin_amdgcn_mfma_scale_f32_16x16x128_f8f6f4(         \
                af[m][1], B1, ACC[m], 0, 0, 0, SCL, 0, SCL);                   \
        __builtin_amdgcn_s_setprio(0);                                         \
    }

    // epilogue for a finished chunk: diag fix + row-max + col-max
    #define EPI(ACC, CB) {                                                     \
        const int cfb_ = (CB) + (wid << 4);                                    \
        if (cfb_ < brow + 128 && cfb_ + 16 > brow) {                           \
            _Pragma("unroll")                                                  \
            for (int m = 0; m < 8; ++m)                                        \
                _Pragma("unroll")                                              \
                for (int r = 0; r < 4; ++r) {                                  \
                    const int gi_ = brow + m * 16 + (rg << 2) + r;             \
                    if (gi_ - cfb_ == cl) ACC[m][r] = -diag[gi_];              \
                }                                                              \
        }                                                                      \
        _Pragma("unroll")                                                      \
        for (int m = 0; m < 8; ++m)                                            \
            _Pragma("unroll")                                                  \
            for (int r = 0; r < 4; ++r)                                        \
                rmx[m][r] = fmaxf(rmx[m][r], ACC[m][r]);                       \
        {                                                                      \
            float v_ = fmaxf(ACC[0][0], ACC[0][1]);                            \
            v_ = fmaxf(fmaxf(v_, ACC[0][2]), ACC[0][3]);                       \
            _Pragma("unroll")                                                  \
            for (int m = 1; m < 8; ++m) {                                      \
                v_ = fmaxf(fmaxf(v_, ACC[m][0]), ACC[m][1]);                   \
                v_ = fmaxf(fmaxf(v_, ACC[m][2]), ACC[m][3]);                   \
            }                                                                  \
            v_ = fmaxf(v_, __shfl_xor(v_, 16));                                \
            v_ = fmaxf(v_, __shfl_xor(v_, 32));                                \
            if (rg == 0) {                                                     \
                const int c_ = cfb_ + cl - scol;                               \
                clds[c_] = fmaxf(clds[c_], v_);                                \
            }                                                                  \
        }                                                                      \
    }

    // prologue: chunk 0 fragments
    int32x8 bA0 = *reinterpret_cast<const int32x8*>(pb);
    int32x8 bA1 = *reinterpret_cast<const int32x8*>(pb + 128);

    for (int h = 0; h < 64; h += 2) {
        // load chunk h+1 (always exists: h <= 62)
        const unsigned char* p1 = pb + ((size_t)(h + 1) << 14);
        int32x8 bB0 = *reinterpret_cast<const int32x8*>(p1);
        int32x8 bB1 = *reinterpret_cast<const int32x8*>(p1 + 128);

        MFMA_CHUNK(accA, bA0, bA1);              // chunk h
        if (h > 0) EPI(accB, scol + ((h - 1) << 6));   // deferred h-1

        // load chunk h+2 (clamped dead reload at tail)
        const int h2 = (h + 2 < 64) ? h + 2 : h;
        const unsigned char* p2 = pb + ((size_t)h2 << 14);
        bA0 = *reinterpret_cast<const int32x8*>(p2);
        bA1 = *reinterpret_cast<const int32x8*>(p2 + 128);

        MFMA_CHUNK(accB, bB0, bB1);              // chunk h+1
        EPI(accA, scol + (h << 6));              // chunk h
    }
    EPI(accB, scol + (63 << 6));                 // tail: chunk 63

    #undef MFMA_CHUNK
    #undef EPI

    // ---- row-max writeout ----
    #pragma unroll
    for (int m = 0; m < 8; ++m)
        #pragma unroll
        for (int r = 0; r < 4; ++r) {
            float v = rmx[m][r];
            v = fmaxf(v, __shfl_xor(v, 1));
            v = fmaxf(v, __shfl_xor(v, 2));
            v = fmaxf(v, __shfl_xor(v, 4));
            v = fmaxf(v, __shfl_xor(v, 8));
            if (cl == 0)
                atomicMax(&rowmax[brow + m * 16 + (rg << 2) + r], fkey(v));
        }

    // ---- flush colmax (batched, once per block) ----
    __syncthreads();
    #pragma unroll
    for (int i = 0; i < 16; ++i) {
        const int c = t + (i << 8);
        atomicMax(&colmax[scol + c], fkey(clds[c]));
    }
}

// ---------------- finalize: hinge + total sum ----------------
__global__ __launch_bounds__(1024) void finalize_kernel(
    const float* __restrict__ diag,
    const unsigned* __restrict__ rowmax,
    const unsigned* __restrict__ colmax,
    float* __restrict__ out) {
    __shared__ float red[1024];
    int t = threadIdx.x;
    float s = 0.f;
    for (int idx = t; idx < 2 * NN; idx += 1024) {
        int i = idx & (NN - 1);
        float mx = fdec((idx < NN) ? colmax[i] : rowmax[i]);
        s += fmaxf(mx + (MARGIN_F - diag[i]), 0.f);
    }
    red[t] = s;
    __syncthreads();
    for (int off = 512; off > 0; off >>= 1) {
        if (t < off) red[t] += red[t + off];
        __syncthreads();
    }
    if (t == 0) out[0] = red[0];
}

extern "C" void kernel_launch(void* const* d_in, const int* in_sizes, int n_in,
                              void* d_out, int out_size, void* d_ws, size_t ws_size,
                              hipStream_t stream) {
    const float* imgs = reinterpret_cast<const float*>(d_in[0]);
    const float* caps = reinterpret_cast<const float*>(d_in[1]);

    float* diag          = reinterpret_cast<float*>(d_ws);
    unsigned* rowmax     = reinterpret_cast<unsigned*>(diag + NN);
    unsigned* colmax     = rowmax + NN;
    unsigned char* imgs8 = reinterpret_cast<unsigned char*>(colmax + NN);
    unsigned char* caps8 = imgs8 + (size_t)NN * DD;

    fused_prep_kernel<<<NN / 4, 256, 0, stream>>>(imgs, caps, imgs8, caps8,
                                                  diag, rowmax, colmax);

    score_max_kernel<<<512, 256, 0, stream>>>(imgs8, caps8, diag,
                                              rowmax, colmax);

    finalize_kernel<<<1, 1024, 0, stream>>>(diag, rowmax, colmax,
                                            reinterpret_cast<float*>(d_out));
}

// Round 21
// 94.666 us; speedup vs baseline: 3.2273x; 3.2273x over previous
//
#include <hip/hip_runtime.h>
#include <hip/hip_bf16.h>
#include <hip/hip_fp8.h>
#include <stdint.h>
#include <math.h>

#define NN 16384
#define DD 256
#define MARGIN_F 0.2f

typedef __attribute__((ext_vector_type(8))) int int32x8;
typedef __attribute__((ext_vector_type(4))) float f32x4;

// monotone order-preserving float<->uint key (max via unsigned atomicMax)
__device__ inline unsigned fkey(float f) {
    unsigned b = __float_as_uint(f);
    return (b & 0x80000000u) ? ~b : (b | 0x80000000u);
}
__device__ inline float fdec(unsigned k) {
    return __uint_as_float((k & 0x80000000u) ? (k ^ 0x80000000u) : ~k);
}
#define NEG_INF_KEY 0x007FFFFFu   // fkey(-inf)

__device__ inline void gload16(const void* g, void* l) {
    __builtin_amdgcn_global_load_lds(
        (const __attribute__((address_space(1))) void*)g,
        (__attribute__((address_space(3))) void*)l, 16, 0, 0);
}

__device__ inline unsigned pk8(float4 v) {
    __hip_fp8_e4m3 q0(v.x), q1(v.y), q2(v.z), q3(v.w);
    return (unsigned)q0.__x | ((unsigned)q1.__x << 8) |
           ((unsigned)q2.__x << 16) | ((unsigned)q3.__x << 24);
}

// ---------------- fused prep: f32->fp8 e4m3 + diag + init maxes ------------
__global__ __launch_bounds__(256) void fused_prep_kernel(
    const float* __restrict__ imgs, const float* __restrict__ caps,
    unsigned char* __restrict__ imgs8, unsigned char* __restrict__ caps8,
    float* __restrict__ diag, unsigned* __restrict__ rowmax,
    unsigned* __restrict__ colmax) {
    const int i = (blockIdx.x << 2) + (threadIdx.x >> 6);
    const int l = threadIdx.x & 63;
    const float4* a4 = reinterpret_cast<const float4*>(imgs + (size_t)i * DD);
    const float4* b4 = reinterpret_cast<const float4*>(caps + (size_t)i * DD);
    float4 av = a4[l];
    float4 bv = b4[l];
    reinterpret_cast<unsigned*>(imgs8 + (size_t)i * DD)[l] = pk8(av);
    reinterpret_cast<unsigned*>(caps8 + (size_t)i * DD)[l] = pk8(bv);
    float s = av.x * bv.x + av.y * bv.y + av.z * bv.z + av.w * bv.w;
    #pragma unroll
    for (int off = 32; off > 0; off >>= 1) s += __shfl_down(s, off);
    if (l == 0) {
        diag[i] = s;
        rowmax[i] = NEG_INF_KEY;
        colmax[i] = NEG_INF_KEY;
    }
}

// ---------------- main: MX-fp8, B global->VGPR, low-latency epilogue -------
// R18 skeleton (proven 83us): 512 blocks = 128 row-panels(128) x 4 strips;
// A panel (32KB fp8) staged once via gload_lds -> af[8][2] (full 128 rows
// per wave); B fragments (32 contiguous bytes/lane, L2-resident) loaded
// straight to VGPRs one chunk ahead; no in-loop barriers.
// NEW vs R18: colmax epilogue latency cut -- tree-shaped 32->1 reduce
// (depth 5) and a single fire-and-forget LDS atomicMax on u32 keys (all 64
// lanes, 4 lanes/address) replacing the serial {2x shfl_xor + clds rmw}
// dependency chain (~300 cyc -> ~30 cyc per chunk).
__global__ __launch_bounds__(256, 2) void score_max_kernel(
    const unsigned char* __restrict__ imgs8,
    const unsigned char* __restrict__ caps8,
    const float* __restrict__ diag,
    unsigned* __restrict__ rowmax, unsigned* __restrict__ colmax) {

    __shared__ char lds[49152];   // [0,32K): A staging; [32K,48K): clds keys
    unsigned* clds = reinterpret_cast<unsigned*>(lds + 32768);

    const int bid   = blockIdx.x;
    const int panel = bid >> 2;
    const int strip = bid & 3;
    const int brow  = panel << 7;       // 128-row panel
    const int scol  = strip << 12;      // 4096-col strip

    const int t    = threadIdx.x;
    const int wid  = t >> 6;      // 0..3: col-slice owner
    const int lane = t & 63;
    const int rg   = lane >> 4;   // 0..3
    const int cl   = lane & 15;   // 0..15

    // ---- init clds (4096 u32 keys) ----
    #pragma unroll
    for (int i = 0; i < 16; ++i) clds[t + (i << 8)] = NEG_INF_KEY;

    // ---- stage A panel (128 rows = 32KB) with 32B-pair XOR swizzle ----
    {
        const int sl = t & 15;
        const int rw = t >> 4;
        const int srcoff = (((sl >> 1) ^ (rw & 7)) << 5) + ((sl & 1) << 4);
        const unsigned char* src =
            imgs8 + (((size_t)(brow + rw)) << 8) + srcoff;
        #pragma unroll
        for (int i = 0; i < 8; ++i)
            gload16(src + ((size_t)i << 12), lds + t * 16 + i * 4096);
    }
    __syncthreads();

    // ---- A fragments: af[m][ks], row = m*16+cl (full 128 rows/wave) ----
    int32x8 af[8][2];
    #pragma unroll
    for (int m = 0; m < 8; ++m) {
        const int row = m * 16 + cl;
        #pragma unroll
        for (int ks = 0; ks < 2; ++ks)
            af[m][ks] = *reinterpret_cast<const int32x8*>(
                lds + row * 256 + (((rg + (ks << 2)) ^ (cl & 7)) << 5));
    }
    // no further shared-LDS hazards in loop: clds combine is via ds atomics

    float rmx[8][4];
    #pragma unroll
    for (int m = 0; m < 8; ++m)
        #pragma unroll
        for (int r = 0; r < 4; ++r) rmx[m][r] = -INFINITY;

    // ---- B base: wave col = scol + wid*16 + cl; 32B at rg*32 ----
    const unsigned char* pb =
        caps8 + (((size_t)(scol + (wid << 4) + cl)) << 8) + (rg << 5);

    const f32x4 zv = (f32x4){0.f, 0.f, 0.f, 0.f};
    #define SCL 0x7F7F7F7F   // E8M0 exponent 127 = 1.0 in every byte

    // prologue: load chunk 0 fragments
    int32x8 b0 = *reinterpret_cast<const int32x8*>(pb);
    int32x8 b1 = *reinterpret_cast<const int32x8*>(pb + 128);

    for (int h = 0; h < 64; ++h) {
        const int cb = scol + (h << 6);
        const int hn = (h < 63) ? h + 1 : h;     // clamp: dead reload at tail
        const unsigned char* pn = pb + ((size_t)hn << 14);

        // issue next chunk's loads (L2 hit; covered by the 16 MFMAs)
        int32x8 bn0 = *reinterpret_cast<const int32x8*>(pn);
        int32x8 bn1 = *reinterpret_cast<const int32x8*>(pn + 128);

        f32x4 acc[8];
        __builtin_amdgcn_s_setprio(1);
        #pragma unroll
        for (int m = 0; m < 8; ++m)
            acc[m] = __builtin_amdgcn_mfma_scale_f32_16x16x128_f8f6f4(
                af[m][0], b0, zv, 0, 0, 0, SCL, 0, SCL);
        #pragma unroll
        for (int m = 0; m < 8; ++m)
            acc[m] = __builtin_amdgcn_mfma_scale_f32_16x16x128_f8f6f4(
                af[m][1], b1, acc[m], 0, 0, 0, SCL, 0, SCL);
        __builtin_amdgcn_s_setprio(0);

        // ---- diagonal fix (exact f32); wave's cols = cfb..cfb+15 ----
        const int cfb = cb + (wid << 4);
        if (cfb < brow + 128 && cfb + 16 > brow) {
            #pragma unroll
            for (int m = 0; m < 8; ++m)
                #pragma unroll
                for (int r = 0; r < 4; ++r) {
                    const int gi = brow + m * 16 + (rg << 2) + r;
                    if (gi - cfb == cl) acc[m][r] = -diag[gi];
                }
        }

        // ---- running row-max (independent ops, no chain) ----
        #pragma unroll
        for (int m = 0; m < 8; ++m)
            #pragma unroll
            for (int r = 0; r < 4; ++r)
                rmx[m][r] = fmaxf(rmx[m][r], acc[m][r]);

        // ---- col-max: depth-5 tree reduce + fire-and-forget LDS atomic ----
        {
            float p[16];
            #pragma unroll
            for (int m = 0; m < 8; ++m) {
                p[2 * m]     = fmaxf(acc[m][0], acc[m][1]);
                p[2 * m + 1] = fmaxf(acc[m][2], acc[m][3]);
            }
            #pragma unroll
            for (int s = 8; s > 0; s >>= 1)
                #pragma unroll
                for (int i = 0; i < s; ++i)
                    p[i] = fmaxf(p[i], p[i + s]);
            // all 64 lanes: 4 lanes per address; DS pipe does the combine,
            // no return value -> no wave-side latency chain
            atomicMax(&clds[cfb + cl - scol], fkey(p[0]));
        }

        b0 = bn0;
        b1 = bn1;
    }

    // ---- row-max writeout ----
    #pragma unroll
    for (int m = 0; m < 8; ++m)
        #pragma unroll
        for (int r = 0; r < 4; ++r) {
            float v = rmx[m][r];
            v = fmaxf(v, __shfl_xor(v, 1));
            v = fmaxf(v, __shfl_xor(v, 2));
            v = fmaxf(v, __shfl_xor(v, 4));
            v = fmaxf(v, __shfl_xor(v, 8));
            if (cl == 0)
                atomicMax(&rowmax[brow + m * 16 + (rg << 2) + r], fkey(v));
        }

    // ---- flush colmax keys (batched, once per block) ----
    __syncthreads();
    #pragma unroll
    for (int i = 0; i < 16; ++i) {
        const int c = t + (i << 8);
        atomicMax(&colmax[scol + c], clds[c]);
    }
}

// ---------------- finalize: hinge + total sum ----------------
__global__ __launch_bounds__(1024) void finalize_kernel(
    const float* __restrict__ diag,
    const unsigned* __restrict__ rowmax,
    const unsigned* __restrict__ colmax,
    float* __restrict__ out) {
    __shared__ float red[1024];
    int t = threadIdx.x;
    float s = 0.f;
    for (int idx = t; idx < 2 * NN; idx += 1024) {
        int i = idx & (NN - 1);
        float mx = fdec((idx < NN) ? colmax[i] : rowmax[i]);
        s += fmaxf(mx + (MARGIN_F - diag[i]), 0.f);
    }
    red[t] = s;
    __syncthreads();
    for (int off = 512; off > 0; off >>= 1) {
        if (t < off) red[t] += red[t + off];
        __syncthreads();
    }
    if (t == 0) out[0] = red[0];
}

extern "C" void kernel_launch(void* const* d_in, const int* in_sizes, int n_in,
                              void* d_out, int out_size, void* d_ws, size_t ws_size,
                              hipStream_t stream) {
    const float* imgs = reinterpret_cast<const float*>(d_in[0]);
    const float* caps = reinterpret_cast<const float*>(d_in[1]);

    float* diag          = reinterpret_cast<float*>(d_ws);
    unsigned* rowmax     = reinterpret_cast<unsigned*>(diag + NN);
    unsigned* colmax     = rowmax + NN;
    unsigned char* imgs8 = reinterpret_cast<unsigned char*>(colmax + NN);
    unsigned char* caps8 = imgs8 + (size_t)NN * DD;

    fused_prep_kernel<<<NN / 4, 256, 0, stream>>>(imgs, caps, imgs8, caps8,
                                                  diag, rowmax, colmax);

    score_max_kernel<<<512, 256, 0, stream>>>(imgs8, caps8, diag,
                                              rowmax, colmax);

    finalize_kernel<<<1, 1024, 0, stream>>>(diag, rowmax, colmax,
                                            reinterpret_cast<float*>(d_out));
}